// Round 3
// baseline (441.799 us; speedup 1.0000x reference)
//
#include <hip/hip_runtime.h>
#include <stdint.h>

#define B_ 8
#define S_ 1024
#define IN_DIM 512
#define DM 1024
#define H_ 16
#define DEP 64

typedef __bf16 bf16;
typedef __attribute__((ext_vector_type(8))) __bf16 bf16x8;
typedef __attribute__((ext_vector_type(4))) __bf16 bf16x4;
typedef __attribute__((ext_vector_type(4))) float f32x4;

// ---------------------------------------------------------------- dtype detect
// flag=1 -> inputs are bf16; flag=0 -> inputs are float32.
// x ~ N(0,1): bf16 view has exponent in [100,140] for ~all words; an f32 array
// viewed as u16 has random exponents in its even (low-half) words.
__global__ void detect_kernel(const uint16_t* __restrict__ xraw, int* __restrict__ flag) {
    const int t = threadIdx.x;  // 64 threads
    int sane = 0;
    #pragma unroll
    for (int j = 0; j < 8; j++) {
        const uint16_t u = xraw[t * 8 + j];
        const int e = (u >> 7) & 0xff;
        sane += ((u & 0x7fff) == 0 || (e >= 100 && e <= 140)) ? 1 : 0;
    }
    #pragma unroll
    for (int m = 1; m < 64; m <<= 1) sane += __shfl_xor(sane, m);
    if (t == 0) *flag = (sane >= 450) ? 1 : 0;
}

static __device__ __forceinline__ float ldin(const void* p, size_t i, int isb) {
    return isb ? (float)((const bf16*)p)[i] : ((const float*)p)[i];
}

// ---------------------------------------------------------------- weights -> bf16 [N][K]
__global__ __launch_bounds__(256) void transpose_kernel(
    const void* __restrict__ wq, const void* __restrict__ wk, const void* __restrict__ wv,
    const void* __restrict__ res, const void* __restrict__ dense,
    bf16* __restrict__ wqT, bf16* __restrict__ wkT, bf16* __restrict__ wvT,
    bf16* __restrict__ resT, bf16* __restrict__ denseT, const int* __restrict__ flag)
{
    const int isb = *flag;
    __shared__ bf16 tile[32][33];
    const int z = blockIdx.z;
    const void* src; bf16* dst; int kb, kd;
    if (z == 0)      { src = wq;    dst = wqT;    kb = 0;   kd = 512;  }
    else if (z == 1) { src = wk;    dst = wkT;    kb = 0;   kd = 512;  }
    else if (z == 2) { src = wv;    dst = wvT;    kb = 0;   kd = 512;  }
    else if (z == 3) { src = res;   dst = resT;   kb = 0;   kd = 512;  }
    else if (z == 4) { src = dense; dst = denseT; kb = 0;   kd = 1024; }
    else             { src = dense; dst = denseT; kb = 512; kd = 1024; }
    const int n0 = blockIdx.x * 32, k0 = blockIdx.y * 32;
    const int tx = threadIdx.x, ty = threadIdx.y;
    #pragma unroll
    for (int r = 0; r < 4; r++)
        tile[ty + r*8][tx] = (bf16)ldin(src, (size_t)(kb + k0 + ty + r*8) * DM + n0 + tx, isb);
    __syncthreads();
    #pragma unroll
    for (int r = 0; r < 4; r++)
        dst[(size_t)(n0 + ty + r*8) * kd + kb + k0 + tx] = tile[tx][ty + r*8];
}

// ---------------------------------------------------------------- x -> bf16
__global__ __launch_bounds__(256) void xconv_kernel(
    const void* __restrict__ x, bf16* __restrict__ xc, const int* __restrict__ flag)
{
    const int isb = *flag;
    const size_t i = ((size_t)blockIdx.x * 256 + threadIdx.x) * 4;
    #pragma unroll
    for (int j = 0; j < 4; j++) xc[i + j] = (bf16)ldin(x, i + j, isb);
}

// ---------------------------------------------------------------- small vectors -> bf16
// order: [wq_b, wk_b, wv_b, dense_b, ln_g, ln_b], each 1024
__global__ __launch_bounds__(256) void smallconv_kernel(
    const void* b0, const void* b1, const void* b2, const void* b3,
    const void* b4, const void* b5, bf16* __restrict__ out, const int* __restrict__ flag)
{
    const int isb = *flag;
    const void* srcs[6] = {b0, b1, b2, b3, b4, b5};
    const void* s = srcs[blockIdx.x];
    for (int i = threadIdx.x; i < 1024; i += 256)
        out[blockIdx.x * 1024 + i] = (bf16)ldin(s, i, isb);
}

// ---------------------------------------------------------------- GEMM core (explicit staging)
template<int KDIM>
static __device__ __forceinline__ void gemm_core(
    const bf16* __restrict__ A, const bf16* __restrict__ BT,
    int m0, int n0, bf16* Asm, bf16* Bsm, f32x4 acc[4][4])
{
    const int tid = threadIdx.x, l = tid & 63, w = tid >> 6;
    const int wm = w >> 1, wn = w & 1, quad = l >> 4, l15 = l & 15;
    #pragma unroll
    for (int i = 0; i < 4; i++)
        #pragma unroll
        for (int j = 0; j < 4; j++) acc[i][j] = f32x4{0.f, 0.f, 0.f, 0.f};

    const int c0 = tid,       r0 = c0 >> 2, h0 = c0 & 3;
    const int c1 = 256 + tid, r1 = c1 >> 2, h1 = c1 & 3;

    for (int k0 = 0; k0 < KDIM; k0 += 32) {
        const bf16x8 a0 = *(const bf16x8*)(A  + (size_t)(m0 + r0)*KDIM + k0 + h0*8);
        const bf16x8 a1 = *(const bf16x8*)(A  + (size_t)(m0 + r1)*KDIM + k0 + h1*8);
        const bf16x8 b0 = *(const bf16x8*)(BT + (size_t)(n0 + r0)*KDIM + k0 + h0*8);
        const bf16x8 b1 = *(const bf16x8*)(BT + (size_t)(n0 + r1)*KDIM + k0 + h1*8);
        __syncthreads();
        *(bf16x8*)(Asm + c0*8) = a0;
        *(bf16x8*)(Asm + c1*8) = a1;
        *(bf16x8*)(Bsm + c0*8) = b0;
        *(bf16x8*)(Bsm + c1*8) = b1;
        __syncthreads();
        bf16x8 af[4], bfv[4];
        #pragma unroll
        for (int i = 0; i < 4; i++)
            af[i] = *(const bf16x8*)(Asm + (wm*64 + i*16 + l15)*32 + quad*8);
        #pragma unroll
        for (int j = 0; j < 4; j++)
            bfv[j] = *(const bf16x8*)(Bsm + (wn*64 + j*16 + l15)*32 + quad*8);
        #pragma unroll
        for (int i = 0; i < 4; i++)
            #pragma unroll
            for (int j = 0; j < 4; j++)
                acc[i][j] = __builtin_amdgcn_mfma_f32_16x16x32_bf16(af[i], bfv[j], acc[i][j], 0, 0, 0);
    }
}

// ---------------------------------------------------------------- QKV + residual projection
__global__ __launch_bounds__(256) void proj_kernel(
    const bf16* __restrict__ x,
    const bf16* __restrict__ wqT, const bf16* __restrict__ wkT,
    const bf16* __restrict__ wvT, const bf16* __restrict__ resT,
    const bf16* __restrict__ small,
    bf16* __restrict__ Q, bf16* __restrict__ K, bf16* __restrict__ V, bf16* __restrict__ R)
{
    __shared__ alignas(16) bf16 Asm[128*32];
    __shared__ alignas(16) bf16 Bsm[128*32];
    const int m0 = blockIdx.x * 128;
    const int ng = blockIdx.y * 128;
    const int sel = ng >> 10, n0 = ng & 1023;
    const bf16* BT; const bf16* bias = nullptr; bf16* OUT = nullptr;
    if (sel == 0)      { BT = wqT; bias = small;        OUT = Q; }
    else if (sel == 1) { BT = wkT; bias = small + 1024; OUT = K; }
    else if (sel == 2) { BT = wvT; bias = small + 2048; OUT = V; }
    else               { BT = resT; }

    f32x4 acc[4][4];
    gemm_core<IN_DIM>(x, BT, m0, n0, Asm, Bsm, acc);

    const int tid = threadIdx.x, l = tid & 63, w = tid >> 6;
    const int wm = w >> 1, wn = w & 1, quad = l >> 4, l15 = l & 15;
    if (sel < 3) {
        #pragma unroll
        for (int j = 0; j < 4; j++) {
            const int col = n0 + wn*64 + j*16 + l15;
            const float bv = (float)bias[col];
            #pragma unroll
            for (int i = 0; i < 4; i++) {
                const int rb = m0 + wm*64 + i*16 + quad*4;
                #pragma unroll
                for (int r = 0; r < 4; r++)
                    OUT[(size_t)(rb + r)*DM + col] = (bf16)(acc[i][j][r] + bv);
            }
        }
    } else {
        #pragma unroll
        for (int j = 0; j < 4; j++) {
            const int col = n0 + wn*64 + j*16 + l15;
            #pragma unroll
            for (int i = 0; i < 4; i++) {
                const int rb = m0 + wm*64 + i*16 + quad*4;
                #pragma unroll
                for (int r = 0; r < 4; r++)
                    R[(size_t)(rb + r)*DM + col] = (bf16)acc[i][j][r];
            }
        }
    }
}

// ---------------------------------------------------------------- flash attention (AO may alias Q)
__global__ __launch_bounds__(256) void attn_kernel(
    const bf16* __restrict__ Q, const bf16* __restrict__ K, const bf16* __restrict__ V,
    const int* __restrict__ mask, bf16* __restrict__ AO)
{
    __shared__ alignas(16) bf16 Ksm[64*72];
    __shared__ alignas(16) bf16 Vt [64*72];
    __shared__ alignas(16) bf16 Psm[4*16*40];

    const int tid = threadIdx.x, l = tid & 63, w = tid >> 6;
    const int quad = l >> 4, l15 = l & 15;
    const int b = blockIdx.y >> 4, h = blockIdx.y & 15;
    const int q0 = blockIdx.x * 64;
    const size_t rowbase = (size_t)b * S_;

    bf16x8 qa[2];
    {
        const bf16* qp = Q + (rowbase + q0 + w*16 + l15)*DM + h*DEP + quad*8;
        qa[0] = *(const bf16x8*)qp;
        qa[1] = *(const bf16x8*)(qp + 32);
    }
    const int* mrow[4];
    #pragma unroll
    for (int r = 0; r < 4; r++)
        mrow[r] = mask + (size_t)h*S_*S_ + (size_t)(q0 + w*16 + quad*4 + r)*S_;

    float m_run[4] = {-INFINITY, -INFINITY, -INFINITY, -INFINITY};
    float l_run[4] = {0.f, 0.f, 0.f, 0.f};
    f32x4 o[4];
    #pragma unroll
    for (int dt = 0; dt < 4; dt++) o[dt] = f32x4{0.f, 0.f, 0.f, 0.f};

    bf16* pp = Psm + w*(16*40);

    for (int kt = 0; kt < S_; kt += 64) {
        __syncthreads();
        #pragma unroll
        for (int qq = 0; qq < 2; qq++) {
            const int c = qq*256 + tid;
            const int row = c >> 3, ch = c & 7;
            const size_t gof = (rowbase + kt + row)*DM + h*DEP + ch*8;
            *(bf16x8*)(Ksm + row*72 + ch*8) = *(const bf16x8*)(K + gof);
            bf16x8 vv = *(const bf16x8*)(V + gof);
            #pragma unroll
            for (int j = 0; j < 8; j++) Vt[(ch*8 + j)*72 + row] = vv[j];
        }
        __syncthreads();

        #pragma unroll
        for (int sub = 0; sub < 2; sub++) {
            f32x4 s2[2];
            #pragma unroll
            for (int h2 = 0; h2 < 2; h2++) {
                const bf16* kp = Ksm + (sub*32 + h2*16 + l15)*72 + quad*8;
                f32x4 z = {0.f, 0.f, 0.f, 0.f};
                z = __builtin_amdgcn_mfma_f32_16x16x32_bf16(qa[0], *(const bf16x8*)kp,        z, 0, 0, 0);
                z = __builtin_amdgcn_mfma_f32_16x16x32_bf16(qa[1], *(const bf16x8*)(kp + 32), z, 0, 0, 0);
                s2[h2] = z;
            }
            const int kc = kt + sub*32 + l15;
            float sv[2][4];
            #pragma unroll
            for (int h2 = 0; h2 < 2; h2++)
                #pragma unroll
                for (int r = 0; r < 4; r++)
                    sv[h2][r] = mrow[r][kc + h2*16] ? s2[h2][r]*0.125f : -1e9f;

            float alpha[4], p0[4], p1[4];
            #pragma unroll
            for (int r = 0; r < 4; r++) {
                float t = fmaxf(sv[0][r], sv[1][r]);
                t = fmaxf(t, __shfl_xor(t, 1));
                t = fmaxf(t, __shfl_xor(t, 2));
                t = fmaxf(t, __shfl_xor(t, 4));
                t = fmaxf(t, __shfl_xor(t, 8));
                const float mn = fmaxf(m_run[r], t);
                alpha[r] = __expf(m_run[r] - mn);
                m_run[r] = mn;
                p0[r] = __expf(sv[0][r] - mn);
                p1[r] = __expf(sv[1][r] - mn);
                float rs = p0[r] + p1[r];
                rs += __shfl_xor(rs, 1);
                rs += __shfl_xor(rs, 2);
                rs += __shfl_xor(rs, 4);
                rs += __shfl_xor(rs, 8);
                l_run[r] = l_run[r]*alpha[r] + rs;
            }
            #pragma unroll
            for (int r = 0; r < 4; r++) {
                pp[(quad*4 + r)*40 + l15]      = (bf16)p0[r];
                pp[(quad*4 + r)*40 + 16 + l15] = (bf16)p1[r];
            }
            __asm__ volatile("s_waitcnt lgkmcnt(0)" ::: "memory");
            #pragma unroll
            for (int dt = 0; dt < 4; dt++)
                #pragma unroll
                for (int r = 0; r < 4; r++) o[dt][r] *= alpha[r];

            bf16x8 pa = *(const bf16x8*)(pp + l15*40 + quad*8);
            #pragma unroll
            for (int dt = 0; dt < 4; dt++) {
                bf16x8 vf = *(const bf16x8*)(Vt + (dt*16 + l15)*72 + sub*32 + quad*8);
                o[dt] = __builtin_amdgcn_mfma_f32_16x16x32_bf16(pa, vf, o[dt], 0, 0, 0);
            }
        }
    }

    #pragma unroll
    for (int r = 0; r < 4; r++) {
        const float inv = 1.0f / l_run[r];
        #pragma unroll
        for (int dt = 0; dt < 4; dt++)
            AO[(rowbase + q0 + w*16 + quad*4 + r)*DM + h*DEP + dt*16 + l15] = (bf16)(o[dt][r]*inv);
    }
}

// ---------------------------------------------------------------- dense + residual (in-place R)
__global__ __launch_bounds__(256) void dense_kernel(
    const bf16* __restrict__ AOin, const bf16* __restrict__ dT,
    const bf16* __restrict__ db, bf16* __restrict__ R)
{
    __shared__ alignas(16) bf16 Asm[128*32];
    __shared__ alignas(16) bf16 Bsm[128*32];
    const int m0 = blockIdx.x * 128, n0 = blockIdx.y * 128;
    f32x4 acc[4][4];
    gemm_core<DM>(AOin, dT, m0, n0, Asm, Bsm, acc);
    const int tid = threadIdx.x, l = tid & 63, w = tid >> 6;
    const int wm = w >> 1, wn = w & 1, quad = l >> 4, l15 = l & 15;
    #pragma unroll
    for (int j = 0; j < 4; j++) {
        const int col = n0 + wn*64 + j*16 + l15;
        const float bv = (float)db[col];
        #pragma unroll
        for (int i = 0; i < 4; i++) {
            const int rb = m0 + wm*64 + i*16 + quad*4;
            #pragma unroll
            for (int r = 0; r < 4; r++) {
                const size_t idx = (size_t)(rb + r)*DM + col;
                R[idx] = (bf16)((float)R[idx] + acc[i][j][r] + bv);
            }
        }
    }
}

// ---------------------------------------------------------------- LayerNorm -> out (bf16 or f32)
__global__ __launch_bounds__(256) void ln_kernel(
    const bf16* __restrict__ R, const bf16* __restrict__ small,
    void* __restrict__ out, const int* __restrict__ flag)
{
    const int isb = *flag;
    __shared__ float red[8];
    const int row = blockIdx.x, tid = threadIdx.x;
    const bf16x4 rv = *(const bf16x4*)(R + (size_t)row*DM + tid*4);
    const float vx = (float)rv[0], vy = (float)rv[1], vz = (float)rv[2], vw = (float)rv[3];
    float s = vx + vy + vz + vw;
    #pragma unroll
    for (int m = 1; m < 64; m <<= 1) s += __shfl_xor(s, m);
    const int w = tid >> 6;
    if ((tid & 63) == 0) red[w] = s;
    __syncthreads();
    const float mu = (red[0] + red[1] + red[2] + red[3]) * (1.0f/DM);
    const float dx = vx - mu, dy = vy - mu, dz = vz - mu, dw = vw - mu;
    float q = dx*dx + dy*dy + dz*dz + dw*dw;
    #pragma unroll
    for (int m = 1; m < 64; m <<= 1) q += __shfl_xor(q, m);
    if ((tid & 63) == 0) red[4 + w] = q;
    __syncthreads();
    const float var = (red[4] + red[5] + red[6] + red[7]) * (1.0f/DM);
    const float rstd = rsqrtf(var + 1e-5f);
    const int col = tid * 4;
    const bf16x4 gv = *(const bf16x4*)(small + 4*1024 + col);
    const bf16x4 bv = *(const bf16x4*)(small + 5*1024 + col);
    const float o0 = dx*rstd*(float)gv[0] + (float)bv[0];
    const float o1 = dy*rstd*(float)gv[1] + (float)bv[1];
    const float o2 = dz*rstd*(float)gv[2] + (float)bv[2];
    const float o3 = dw*rstd*(float)gv[3] + (float)bv[3];
    if (isb) {
        bf16x4 ov; ov[0] = (bf16)o0; ov[1] = (bf16)o1; ov[2] = (bf16)o2; ov[3] = (bf16)o3;
        *(bf16x4*)((bf16*)out + (size_t)row*DM + col) = ov;
    } else {
        float4 ov = {o0, o1, o2, o3};
        *(float4*)((float*)out + (size_t)row*DM + col) = ov;
    }
}

// ---------------------------------------------------------------- launch
extern "C" void kernel_launch(void* const* d_in, const int* in_sizes, int n_in,
                              void* d_out, int out_size, void* d_ws, size_t ws_size,
                              hipStream_t stream) {
    const int* mask = (const int*)d_in[1];

    char* ws = (char*)d_ws;
    bf16* wqT   = (bf16*)(ws);
    bf16* wkT   = (bf16*)(ws + ((size_t)1 << 20));
    bf16* wvT   = (bf16*)(ws + ((size_t)2 << 20));
    bf16* resT  = (bf16*)(ws + ((size_t)3 << 20));
    bf16* dT    = (bf16*)(ws + ((size_t)4 << 20));   // 2 MB
    bf16* small = (bf16*)(ws + ((size_t)6 << 20));   // 12 KB
    int*  flag  = (int*) (ws + ((size_t)6 << 20) + 16384);
    bf16* Qb    = (bf16*)(ws + ((size_t)8  << 20));  // 16 MB (also AO)
    bf16* Kb    = (bf16*)(ws + ((size_t)24 << 20));
    bf16* Vb    = (bf16*)(ws + ((size_t)40 << 20));
    bf16* R     = (bf16*)(ws + ((size_t)56 << 20));  // 16 MB; total 72 MB
    bf16* xc    = (bf16*)d_out;                      // dead until ln_kernel

    detect_kernel<<<1, 64, 0, stream>>>((const uint16_t*)d_in[0], flag);
    transpose_kernel<<<dim3(32, 16, 6), dim3(32, 8), 0, stream>>>(
        d_in[2], d_in[4], d_in[6], d_in[10], d_in[8],
        wqT, wkT, wvT, resT, dT, flag);
    xconv_kernel<<<4096, 256, 0, stream>>>(d_in[0], xc, flag);
    smallconv_kernel<<<6, 256, 0, stream>>>(
        d_in[3], d_in[5], d_in[7], d_in[9], d_in[11], d_in[12], small, flag);
    proj_kernel<<<dim3(64, 32), 256, 0, stream>>>(
        xc, wqT, wkT, wvT, resT, small, Qb, Kb, Vb, R);
    attn_kernel<<<dim3(16, 128), 256, 0, stream>>>(Qb, Kb, Vb, mask, Qb /*AO aliases Q*/);
    dense_kernel<<<dim3(64, 8), 256, 0, stream>>>(Qb, dT, small + 3*1024, R);
    ln_kernel<<<8192, 256, 0, stream>>>(R, small, d_out, flag);
}